// Round 8
// baseline (293.085 us; speedup 1.0000x reference)
//
#include <hip/hip_runtime.h>
#include <hip/hip_bf16.h>

typedef __hip_bfloat16 bf16;
typedef __attribute__((ext_vector_type(8))) short short8b;
typedef __attribute__((ext_vector_type(4))) short short4b;
typedef __attribute__((ext_vector_type(4))) float f32x4;

#define NAREA 2025
#define NAREA_PAD 2048

static __device__ __forceinline__ float b2f(bf16 x) { return __bfloat162float(x); }
static __device__ __forceinline__ short f2bs(float f) {
  bf16 h = __float2bfloat16(f);
  return *(short*)&h;
}
static __device__ __forceinline__ float s2f(short s) {
  return __uint_as_float(((unsigned)(unsigned short)s) << 16);
}

// ---------------------------------------------------------------------------
// Cast x and wqkv to bf16 (layout-preserving)
// ---------------------------------------------------------------------------
__global__ __launch_bounds__(256) void k_cast(
    const float* __restrict__ x, const float* __restrict__ wqkv,
    bf16* __restrict__ xb, bf16* __restrict__ wqkvb)
{
  int idx = (blockIdx.x * 256 + threadIdx.x) * 4;
  const int NX = 4096 * 768;
  float4 v;
  bf16* d;
  if (idx < NX) { v = *(const float4*)(x + idx); d = xb + idx; }
  else { v = *(const float4*)(wqkv + (idx - NX)); d = wqkvb + (idx - NX); }
  short4b s = {f2bs(v.x), f2bs(v.y), f2bs(v.z), f2bs(v.w)};
  *(short4b*)d = s;
}

// ---------------------------------------------------------------------------
// Transpose-cast 768x768 fp32 -> bf16 (dst[n][k] = src[k][n]); z picks matrix
// ---------------------------------------------------------------------------
__global__ __launch_bounds__(256) void k_tcast(
    const float* __restrict__ s0, const float* __restrict__ s1,
    const float* __restrict__ s2, bf16* __restrict__ d0,
    bf16* __restrict__ d1, bf16* __restrict__ d2)
{
  __shared__ float tile[32][33];
  int z = blockIdx.z;
  const float* src = (z == 0) ? s0 : (z == 1) ? s1 : s2;
  bf16* dst = (z == 0) ? d0 : (z == 1) ? d1 : d2;
  int r0 = blockIdx.y * 32, c0 = blockIdx.x * 32;
  int lx = threadIdx.x & 31, ly = threadIdx.x >> 5;
#pragma unroll
  for (int yy = 0; yy < 4; ++yy)
    tile[ly + yy * 8][lx] = src[(size_t)(r0 + ly + yy * 8) * 768 + c0 + lx];
  __syncthreads();
#pragma unroll
  for (int yy = 0; yy < 4; ++yy)
    dst[(size_t)(c0 + ly + yy * 8) * 768 + r0 + lx] =
        __float2bfloat16(tile[lx][ly + yy * 8]);
}

// ===========================================================================
// MFMA GEMM core (BM=128,BN=128,BK=32, 256 thr, 1 barrier/K-tile)
// ===========================================================================

// Wc^T[t][n][m] (bf16) = (wqkv[:,t] @ w_{q,k,v})^T
__global__ __launch_bounds__(256) void k_combine_m(
    const bf16* __restrict__ wqkvb, const bf16* __restrict__ wqT,
    const bf16* __restrict__ wkT, const bf16* __restrict__ wvT,
    bf16* __restrict__ WcTb)
{
  __shared__ __align__(16) short As[2][128 * 32];
  __shared__ __align__(16) short Bs[2][128 * 32];
  const int t3 = blockIdx.z;
  const bf16* BT = (t3 == 0) ? wqT : (t3 == 1) ? wkT : wvT;
  const int m0 = blockIdx.y * 128, n0 = blockIdx.x * 128;
  const int tid = threadIdx.x, lane = tid & 63, w = tid >> 6;
  const int tt = lane & 15, q4 = lane >> 4;
  const int moff = (w & 1) * 64, noff = (w >> 1) * 64;
  const int r_a = tid >> 2, kc = (tid & 3) * 8;

  f32x4 acc[4][4];
#pragma unroll
  for (int i = 0; i < 4; ++i)
#pragma unroll
    for (int j = 0; j < 4; ++j) acc[i][j] = (f32x4){0.f, 0.f, 0.f, 0.f};

  uint4 ra0 = *(const uint4*)(wqkvb + (size_t)(m0 + r_a) * 2304 + t3 * 768 + kc);
  uint4 ra1 = *(const uint4*)(wqkvb + (size_t)(m0 + r_a + 64) * 2304 + t3 * 768 + kc);
  uint4 rb0 = *(const uint4*)(BT + (size_t)(n0 + r_a) * 768 + kc);
  uint4 rb1 = *(const uint4*)(BT + (size_t)(n0 + r_a + 64) * 768 + kc);

  for (int it = 0; it < 24; ++it) {
    short* as = As[it & 1];
    short* bs = Bs[it & 1];
    *(uint4*)&as[r_a * 32 + kc] = ra0;
    *(uint4*)&as[(r_a + 64) * 32 + kc] = ra1;
    *(uint4*)&bs[r_a * 32 + kc] = rb0;
    *(uint4*)&bs[(r_a + 64) * 32 + kc] = rb1;
    if (it < 23) {
      int k0 = (it + 1) * 32;
      ra0 = *(const uint4*)(wqkvb + (size_t)(m0 + r_a) * 2304 + t3 * 768 + k0 + kc);
      ra1 = *(const uint4*)(wqkvb + (size_t)(m0 + r_a + 64) * 2304 + t3 * 768 + k0 + kc);
      rb0 = *(const uint4*)(BT + (size_t)(n0 + r_a) * 768 + k0 + kc);
      rb1 = *(const uint4*)(BT + (size_t)(n0 + r_a + 64) * 768 + k0 + kc);
    }
    __syncthreads();
    short8b afr[4], bfr[4];
#pragma unroll
    for (int mt = 0; mt < 4; ++mt)
      afr[mt] = *(const short8b*)&as[(moff + mt * 16 + tt) * 32 + q4 * 8];
#pragma unroll
    for (int nt = 0; nt < 4; ++nt)
      bfr[nt] = *(const short8b*)&bs[(noff + nt * 16 + tt) * 32 + q4 * 8];
#pragma unroll
    for (int mt = 0; mt < 4; ++mt)
#pragma unroll
      for (int nt = 0; nt < 4; ++nt)
        acc[mt][nt] = __builtin_amdgcn_mfma_f32_16x16x32_bf16(afr[mt], bfr[nt], acc[mt][nt], 0, 0, 0);
  }

  bf16* C = WcTb + (size_t)t3 * 768 * 768;
#pragma unroll
  for (int nt = 0; nt < 4; ++nt) {
    int n = n0 + noff + nt * 16 + tt;
#pragma unroll
    for (int mt = 0; mt < 4; ++mt) {
      int mb = m0 + moff + mt * 16 + q4 * 4;
      short4b v = {f2bs(acc[mt][nt][0]), f2bs(acc[mt][nt][1]),
                   f2bs(acc[mt][nt][2]), f2bs(acc[mt][nt][3])};
      *(short4b*)&C[(size_t)n * 768 + mb] = v;
    }
  }
}

// qh/kh/vh = xb @ Wc[t] + bias, scattered to [(b*12+h)][n][d] bf16
__global__ __launch_bounds__(256) void k_proj_m(
    const bf16* __restrict__ xb, const bf16* __restrict__ WcTb,
    const float* __restrict__ bq, const float* __restrict__ bk,
    const float* __restrict__ bv,
    bf16* __restrict__ qh, bf16* __restrict__ kh, bf16* __restrict__ vh)
{
  __shared__ __align__(16) short As[2][128 * 32];
  __shared__ __align__(16) short Bs[2][128 * 32];
  const int t3 = blockIdx.z;
  const bf16* BT = WcTb + (size_t)t3 * 768 * 768;
  const float* bias = (t3 == 0) ? bq : (t3 == 1) ? bk : bv;
  bf16* dst = (t3 == 0) ? qh : (t3 == 1) ? kh : vh;
  const int m0 = blockIdx.y * 128, n0 = blockIdx.x * 128;
  const int tid = threadIdx.x, lane = tid & 63, w = tid >> 6;
  const int tt = lane & 15, q4 = lane >> 4;
  const int moff = (w & 1) * 64, noff = (w >> 1) * 64;
  const int r_a = tid >> 2, kc = (tid & 3) * 8;

  f32x4 acc[4][4];
#pragma unroll
  for (int i = 0; i < 4; ++i)
#pragma unroll
    for (int j = 0; j < 4; ++j) acc[i][j] = (f32x4){0.f, 0.f, 0.f, 0.f};

  uint4 ra0 = *(const uint4*)(xb + (size_t)(m0 + r_a) * 768 + kc);
  uint4 ra1 = *(const uint4*)(xb + (size_t)(m0 + r_a + 64) * 768 + kc);
  uint4 rb0 = *(const uint4*)(BT + (size_t)(n0 + r_a) * 768 + kc);
  uint4 rb1 = *(const uint4*)(BT + (size_t)(n0 + r_a + 64) * 768 + kc);

  for (int it = 0; it < 24; ++it) {
    short* as = As[it & 1];
    short* bs = Bs[it & 1];
    *(uint4*)&as[r_a * 32 + kc] = ra0;
    *(uint4*)&as[(r_a + 64) * 32 + kc] = ra1;
    *(uint4*)&bs[r_a * 32 + kc] = rb0;
    *(uint4*)&bs[(r_a + 64) * 32 + kc] = rb1;
    if (it < 23) {
      int k0 = (it + 1) * 32;
      ra0 = *(const uint4*)(xb + (size_t)(m0 + r_a) * 768 + k0 + kc);
      ra1 = *(const uint4*)(xb + (size_t)(m0 + r_a + 64) * 768 + k0 + kc);
      rb0 = *(const uint4*)(BT + (size_t)(n0 + r_a) * 768 + k0 + kc);
      rb1 = *(const uint4*)(BT + (size_t)(n0 + r_a + 64) * 768 + k0 + kc);
    }
    __syncthreads();
    short8b afr[4], bfr[4];
#pragma unroll
    for (int mt = 0; mt < 4; ++mt)
      afr[mt] = *(const short8b*)&as[(moff + mt * 16 + tt) * 32 + q4 * 8];
#pragma unroll
    for (int nt = 0; nt < 4; ++nt)
      bfr[nt] = *(const short8b*)&bs[(noff + nt * 16 + tt) * 32 + q4 * 8];
#pragma unroll
    for (int mt = 0; mt < 4; ++mt)
#pragma unroll
      for (int nt = 0; nt < 4; ++nt)
        acc[mt][nt] = __builtin_amdgcn_mfma_f32_16x16x32_bf16(afr[mt], bfr[nt], acc[mt][nt], 0, 0, 0);
  }

#pragma unroll
  for (int nt = 0; nt < 4; ++nt) {
    int c = n0 + noff + nt * 16 + tt;
    float bvv = bias[c];
    int h = c >> 6, d = c & 63;
#pragma unroll
    for (int mt = 0; mt < 4; ++mt) {
#pragma unroll
      for (int r = 0; r < 4; ++r) {
        int m = m0 + moff + mt * 16 + q4 * 4 + r;
        dst[(((size_t)((m >> 8) * 12 + h)) << 14) + ((m & 255) << 6) + d] =
            __float2bfloat16(acc[mt][nt][r] + bvv);
      }
    }
  }
}

// out = gather(attno) @ wo + bo (fp32 out)
__global__ __launch_bounds__(256) void k_out_m(
    const bf16* __restrict__ attno, const bf16* __restrict__ woT,
    const float* __restrict__ bo, float* __restrict__ out)
{
  __shared__ __align__(16) short As[2][128 * 32];
  __shared__ __align__(16) short Bs[2][128 * 32];
  const int m0 = blockIdx.y * 128, n0 = blockIdx.x * 128;
  const int tid = threadIdx.x, lane = tid & 63, w = tid >> 6;
  const int tt = lane & 15, q4 = lane >> 4;
  const int moff = (w & 1) * 64, noff = (w >> 1) * 64;
  const int r_a = tid >> 2, kc = (tid & 3) * 8;

  f32x4 acc[4][4];
#pragma unroll
  for (int i = 0; i < 4; ++i)
#pragma unroll
    for (int j = 0; j < 4; ++j) acc[i][j] = (f32x4){0.f, 0.f, 0.f, 0.f};

  int m_a0 = m0 + r_a, m_a1 = m0 + r_a + 64;
  uint4 ra0 = *(const uint4*)(attno + (((size_t)((m_a0 >> 8) * 12 + (kc >> 6))) << 14) + ((m_a0 & 255) << 6) + (kc & 63));
  uint4 ra1 = *(const uint4*)(attno + (((size_t)((m_a1 >> 8) * 12 + (kc >> 6))) << 14) + ((m_a1 & 255) << 6) + (kc & 63));
  uint4 rb0 = *(const uint4*)(woT + (size_t)(n0 + r_a) * 768 + kc);
  uint4 rb1 = *(const uint4*)(woT + (size_t)(n0 + r_a + 64) * 768 + kc);

  for (int it = 0; it < 24; ++it) {
    short* as = As[it & 1];
    short* bs = Bs[it & 1];
    *(uint4*)&as[r_a * 32 + kc] = ra0;
    *(uint4*)&as[(r_a + 64) * 32 + kc] = ra1;
    *(uint4*)&bs[r_a * 32 + kc] = rb0;
    *(uint4*)&bs[(r_a + 64) * 32 + kc] = rb1;
    if (it < 23) {
      int k = (it + 1) * 32 + kc;
      ra0 = *(const uint4*)(attno + (((size_t)((m_a0 >> 8) * 12 + (k >> 6))) << 14) + ((m_a0 & 255) << 6) + (k & 63));
      ra1 = *(const uint4*)(attno + (((size_t)((m_a1 >> 8) * 12 + (k >> 6))) << 14) + ((m_a1 & 255) << 6) + (k & 63));
      rb0 = *(const uint4*)(woT + (size_t)(n0 + r_a) * 768 + k);
      rb1 = *(const uint4*)(woT + (size_t)(n0 + r_a + 64) * 768 + k);
    }
    __syncthreads();
    short8b afr[4], bfr[4];
#pragma unroll
    for (int mt = 0; mt < 4; ++mt)
      afr[mt] = *(const short8b*)&as[(moff + mt * 16 + tt) * 32 + q4 * 8];
#pragma unroll
    for (int nt = 0; nt < 4; ++nt)
      bfr[nt] = *(const short8b*)&bs[(noff + nt * 16 + tt) * 32 + q4 * 8];
#pragma unroll
    for (int mt = 0; mt < 4; ++mt)
#pragma unroll
      for (int nt = 0; nt < 4; ++nt)
        acc[mt][nt] = __builtin_amdgcn_mfma_f32_16x16x32_bf16(afr[mt], bfr[nt], acc[mt][nt], 0, 0, 0);
  }

#pragma unroll
  for (int nt = 0; nt < 4; ++nt) {
    int c = n0 + noff + nt * 16 + tt;
    float bvv = bo[c];
#pragma unroll
    for (int mt = 0; mt < 4; ++mt)
#pragma unroll
      for (int r = 0; r < 4; ++r) {
        int m = m0 + moff + mt * 16 + q4 * 4 + r;
        out[(size_t)m * 768 + c] = acc[mt][nt][r] + bvv;
      }
  }
}

// ---------------------------------------------------------------------------
// Area rect table (bh-independent): corner offsets into 17x17x64 SAT + 1/size
// ---------------------------------------------------------------------------
__global__ __launch_bounds__(256) void k_rect(int4* __restrict__ rectG,
                                              float* __restrict__ invG)
{
  int m = blockIdx.x * 256 + threadIdx.x;
  if (m >= NAREA_PAD) return;
  int4 rc = make_int4(0, 0, 0, 0);
  float iv = 0.f;
  if (m < NAREA) {
    int rem = m, ah = 1, aw = 1, found = 0;
    for (int a = 1; a <= 3 && !found; ++a)
      for (int w = 1; w <= 3 && !found; ++w) {
        int np = (17 - a) * (17 - w);
        if (rem < np) { ah = a; aw = w; found = 1; }
        else rem -= np;
      }
    int cw = 17 - aw;
    int y = rem / cw, x = rem - y * cw;
    rc.x = (y * 17 + x) * 64;
    rc.y = (y * 17 + (x + aw)) * 64;
    rc.z = ((y + ah) * 17 + x) * 64;
    rc.w = ((y + ah) * 17 + (x + aw)) * 64;
    iv = 1.0f / (float)(ah * aw);
  }
  rectG[m] = rc;
  invG[m] = iv;
}

// ---------------------------------------------------------------------------
// Integral images: Ik/Iv[bh][17][17][64] fp32
// ---------------------------------------------------------------------------
__global__ __launch_bounds__(128) void k_integral(
    const bf16* __restrict__ kh, const bf16* __restrict__ vh,
    float* __restrict__ Ik, float* __restrict__ Iv)
{
  int bh = blockIdx.x;
  int d = threadIdx.x & 63;
  bool isv = threadIdx.x >= 64;
  const bf16* src = (isv ? vh : kh) + ((size_t)bh << 14);
  float* dst = (isv ? Iv : Ik) + (size_t)bh * 18496;
  float prev[17];
#pragma unroll
  for (int i = 0; i < 17; ++i) prev[i] = 0.f;
#pragma unroll
  for (int xx = 0; xx < 17; ++xx) dst[xx * 64 + d] = 0.f;
#pragma unroll 1
  for (int y = 1; y <= 16; ++y) {
    dst[(y * 17) * 64 + d] = 0.f;
    float rs = 0.f;
#pragma unroll
    for (int xx = 1; xx <= 16; ++xx) {
      rs += b2f(src[((y - 1) * 16 + (xx - 1)) * 64 + d]);
      float cur = prev[xx] + rs;
      dst[(y * 17 + xx) * 64 + d] = cur;
      prev[xx] = cur;
    }
  }
}

// ---------------------------------------------------------------------------
// MFMA flash attention, area-split 4x: block = (bh, split of 512 areas).
// 768 blocks -> 3/CU, 2 co-resident (8 waves/SIMD). Outputs UNNORMALIZED
// partial O (bf16) + partial l (bf16); k_merge combines.
// __launch_bounds__(1024,8): forces VGPR<=64 so 2 blocks/CU fit (LDS 2x72KB).
// aVt staging write packed to one short4b/lane (was 4x b16 8-way conflicts).
// ---------------------------------------------------------------------------
__global__ __launch_bounds__(1024, 8) void k_attn_m(
    const bf16* __restrict__ qh, const float* __restrict__ Ik,
    const float* __restrict__ Iv, const int4* __restrict__ rectG,
    const float* __restrict__ invG, bf16* __restrict__ opA,
    bf16* __restrict__ opB, bf16* __restrict__ lp)
{
  __shared__ __align__(16) short aK2[2][64 * 72];
  __shared__ __align__(16) short aVt2[2][64 * 72];
  __shared__ __align__(16) short Pb[16][16 * 72];

  const int tid = threadIdx.x;
  const int lane = tid & 63;
  const int w = tid >> 6;
  const int t = lane & 15;
  const int q4 = lane >> 4;
  const int bh = blockIdx.x >> 2;
  const int split = blockIdx.x & 3;
  const int itBeg = split * 8, itEnd = itBeg + 8;

  const float* Ikb = Ik + (size_t)bh * 18496;
  const float* Ivb = Iv + (size_t)bh * 18496;
  const bf16* qbase = qh + ((size_t)bh << 14);

  short8b qf0 = *(const short8b*)(qbase + (w * 16 + t) * 64 + q4 * 8);
  short8b qf1 = *(const short8b*)(qbase + (w * 16 + t) * 64 + 32 + q4 * 8);

  f32x4 O[4];
#pragma unroll
  for (int i = 0; i < 4; ++i) O[i] = (f32x4){0.f, 0.f, 0.f, 0.f};
  float l = 0.f;

  {
    short* aK = aK2[itBeg & 1];
    short* aVt = aVt2[itBeg & 1];
    short vp[4];
#pragma unroll
    for (int i = 0; i < 4; ++i) {
      int j = itBeg * 64 + w * 4 + i;
      int4 rc = rectG[j];
      float iv = invG[j];
      float kc = Ikb[rc.w + lane] - Ikb[rc.y + lane] - Ikb[rc.z + lane] + Ikb[rc.x + lane];
      float vc = Ivb[rc.w + lane] - Ivb[rc.y + lane] - Ivb[rc.z + lane] + Ivb[rc.x + lane];
      aK[(w * 4 + i) * 72 + lane] = f2bs(kc * iv);
      vp[i] = f2bs(vc);
    }
    *(short4b*)&aVt[lane * 72 + w * 4] = (short4b){vp[0], vp[1], vp[2], vp[3]};
  }

  for (int it = itBeg; it < itEnd; ++it) {
    __syncthreads();
    const short* aK = aK2[it & 1];
    const short* aVt = aVt2[it & 1];
    if (it + 1 < itEnd) {
      int t0n = (it + 1) * 64;
      short* aKn = aK2[(it + 1) & 1];
      short* aVtn = aVt2[(it + 1) & 1];
      short vp[4];
#pragma unroll
      for (int i = 0; i < 4; ++i) {
        int j = w * 4 + i;
        int4 rc = rectG[t0n + j];
        float iv = invG[t0n + j];
        float kc = Ikb[rc.w + lane] - Ikb[rc.y + lane] - Ikb[rc.z + lane] + Ikb[rc.x + lane];
        float vc = Ivb[rc.w + lane] - Ivb[rc.y + lane] - Ivb[rc.z + lane] + Ivb[rc.x + lane];
        aKn[j * 72 + lane] = f2bs(kc * iv);
        vp[i] = f2bs(vc);
      }
      *(short4b*)&aVtn[lane * 72 + w * 4] = (short4b){vp[0], vp[1], vp[2], vp[3]};
    }

    const int t0 = it * 64;
    const bool edge = (t0 + 64 > NAREA);
#pragma unroll
    for (int at = 0; at < 4; ++at) {
      short8b af0 = *(const short8b*)&aK[(at * 16 + t) * 72 + q4 * 8];
      short8b af1 = *(const short8b*)&aK[(at * 16 + t) * 72 + 32 + q4 * 8];
      f32x4 s = (f32x4){0.f, 0.f, 0.f, 0.f};
      s = __builtin_amdgcn_mfma_f32_16x16x32_bf16(af0, qf0, s, 0, 0, 0);
      s = __builtin_amdgcn_mfma_f32_16x16x32_bf16(af1, qf1, s, 0, 0, 0);
      float p[4];
#pragma unroll
      for (int r = 0; r < 4; ++r) {
        p[r] = __expf(s[r]);
        if (edge && (t0 + at * 16 + q4 * 4 + r >= NAREA)) p[r] = 0.f;
      }
      l += (p[0] + p[1]) + (p[2] + p[3]);
      short4b pk = (short4b){f2bs(p[0]), f2bs(p[1]), f2bs(p[2]), f2bs(p[3])};
      *(short4b*)&Pb[w][t * 72 + at * 16 + q4 * 4] = pk;
    }
    short8b pf0 = *(const short8b*)&Pb[w][t * 72 + q4 * 8];
    short8b pf1 = *(const short8b*)&Pb[w][t * 72 + 32 + q4 * 8];
#pragma unroll
    for (int nt = 0; nt < 4; ++nt) {
      short8b vf0 = *(const short8b*)&aVt[(nt * 16 + t) * 72 + q4 * 8];
      short8b vf1 = *(const short8b*)&aVt[(nt * 16 + t) * 72 + 32 + q4 * 8];
      O[nt] = __builtin_amdgcn_mfma_f32_16x16x32_bf16(pf0, vf0, O[nt], 0, 0, 0);
      O[nt] = __builtin_amdgcn_mfma_f32_16x16x32_bf16(pf1, vf1, O[nt], 0, 0, 0);
    }
  }

  // reduce l across quads -> lane (t,*) holds denom for query w*16+t
  l += __shfl_xor(l, 16, 64);
  l += __shfl_xor(l, 32, 64);
  if (lane < 16)
    lp[(size_t)split * 49152 + bh * 256 + w * 16 + lane] = __float2bfloat16(l);

  bf16* ob = ((split < 2) ? opA + (size_t)split * 3145728
                          : opB + (size_t)(split - 2) * 3145728) +
             ((size_t)bh << 14);
#pragma unroll
  for (int r = 0; r < 4; ++r) {
    int qrow = q4 * 4 + r;
#pragma unroll
    for (int nt = 0; nt < 4; ++nt)
      ob[(w * 16 + qrow) * 64 + nt * 16 + t] = __float2bfloat16(O[nt][r]);
  }
}

// ---------------------------------------------------------------------------
// Merge 4 partials: attno = (sum_s O_s) / (sum_s l_s)
// ---------------------------------------------------------------------------
__global__ __launch_bounds__(256) void k_merge(
    const bf16* __restrict__ opA, const bf16* __restrict__ opB,
    const bf16* __restrict__ lp, bf16* __restrict__ attno)
{
  int gid = blockIdx.x * 256 + threadIdx.x;   // 786432 total
  int bq = gid >> 4;
  int d0 = (gid & 15) * 4;
  size_t off = (size_t)bq * 64 + d0;
  float a0 = 0.f, a1 = 0.f, a2 = 0.f, a3 = 0.f, l = 0.f;
#pragma unroll
  for (int s = 0; s < 4; ++s) {
    const bf16* op = (s < 2) ? opA + (size_t)s * 3145728
                             : opB + (size_t)(s - 2) * 3145728;
    short4b o = *(const short4b*)(op + off);
    a0 += s2f(o.x); a1 += s2f(o.y); a2 += s2f(o.z); a3 += s2f(o.w);
    l += b2f(lp[(size_t)s * 49152 + bq]);
  }
  float inv = 1.0f / l;
  short4b r = {f2bs(a0 * inv), f2bs(a1 * inv), f2bs(a2 * inv), f2bs(a3 * inv)};
  *(short4b*)(attno + off) = r;
}

extern "C" void kernel_launch(void* const* d_in, const int* in_sizes, int n_in,
                              void* d_out, int out_size, void* d_ws, size_t ws_size,
                              hipStream_t stream) {
  const float* x    = (const float*)d_in[0];
  const float* wqkv = (const float*)d_in[1];
  const float* wq   = (const float*)d_in[2];
  const float* bq   = (const float*)d_in[3];
  const float* wk   = (const float*)d_in[4];
  const float* bk   = (const float*)d_in[5];
  const float* wv   = (const float*)d_in[6];
  const float* bv   = (const float*)d_in[7];
  const float* wo   = (const float*)d_in[8];
  const float* bo   = (const float*)d_in[9];
  float* out = (float*)d_out;

  char* ws = (char*)d_ws;
  char* ob = (char*)d_out;
  const size_t WC_B = 7077888;   // zone A size
  const size_t QH_B = 6291456;   // bf16 [192][256][64]

  // d_out as scratch until k_out_m: xb + WcTb (pre-attn), opB (attn partials 2,3)
  bf16* xb    = (bf16*)ob;                  // [0, 6291456)
  bf16* WcTb  = (bf16*)(ob + QH_B);         // [6291456, 9830400)
  bf16* opB   = (bf16*)ob;                  // attn partials: [0, 12582912)
  // ws zone A: attno [0,6291456), rectG/invG, lpart
  bf16* attno = (bf16*)ws;
  int4*  rectG = (int4*)(ws + QH_B);             // [6291456, 6324224)
  float* invG  = (float*)(ws + QH_B + 32768);    // [6324224, 6332416)
  bf16*  lp    = (bf16*)(ws + QH_B + 40960);     // [6332416, 6725632) < 7077888
  // qh/kh/vh
  bf16* qh = (bf16*)(ws + WC_B);
  bf16* kh = (bf16*)(ws + WC_B + QH_B);
  bf16* vh = (bf16*)(ws + WC_B + 2 * QH_B);
  bf16* opA = kh;                                // kh+vh dead after k_integral
  // pre-k_proj aliases into (not-yet-written) qh/kh region
  bf16* wqkvb = (bf16*)(ws + WC_B);
  bf16* wqT   = (bf16*)(ws + WC_B + 3538944);
  bf16* wkT   = (bf16*)(ws + WC_B + 4718592);
  bf16* wvT   = (bf16*)(ws + WC_B + 5898240);
  // SAT; woT aliases dead Ik after attn
  float* Ik = (float*)(ws + WC_B + 3 * QH_B);
  float* Iv = Ik + 3551232;                      // total 54,362,112 (known fit)
  bf16* woT = (bf16*)(ws + WC_B + 3 * QH_B);

  k_cast<<<dim3(4800), 256, 0, stream>>>(x, wqkv, xb, wqkvb);
  k_tcast<<<dim3(24, 24, 3), 256, 0, stream>>>(wq, wk, wv, wqT, wkT, wvT);
  k_combine_m<<<dim3(6, 6, 3), 256, 0, stream>>>(wqkvb, wqT, wkT, wvT, WcTb);
  k_proj_m<<<dim3(6, 32, 3), 256, 0, stream>>>(xb, WcTb, bq, bk, bv, qh, kh, vh);
  k_rect<<<dim3(8), 256, 0, stream>>>(rectG, invG);
  k_integral<<<dim3(192), 128, 0, stream>>>(kh, vh, Ik, Iv);
  k_attn_m<<<dim3(768), 1024, 0, stream>>>(qh, Ik, Iv, rectG, invG, opA, opB, lp);
  k_merge<<<dim3(3072), 256, 0, stream>>>(opA, opB, lp, attno);
  k_tcast<<<dim3(24, 24, 1), 256, 0, stream>>>(wo, wo, wo, woT, woT, woT);
  k_out_m<<<dim3(6, 32), 256, 0, stream>>>(attno, woT, bo, out);
}

// Round 9
// 242.673 us; speedup vs baseline: 1.2077x; 1.2077x over previous
//
#include <hip/hip_runtime.h>
#include <hip/hip_bf16.h>

typedef __hip_bfloat16 bf16;
typedef __attribute__((ext_vector_type(8))) short short8b;
typedef __attribute__((ext_vector_type(4))) short short4b;
typedef __attribute__((ext_vector_type(4))) float f32x4;

#define NAREA 2025
#define NAREA_PAD 2048

static __device__ __forceinline__ float b2f(bf16 x) { return __bfloat162float(x); }
static __device__ __forceinline__ short f2bs(float f) {
  bf16 h = __float2bfloat16(f);
  return *(short*)&h;
}

// ---------------------------------------------------------------------------
// Fused prep: blocks [0,4800) cast x+wqkv -> bf16; [4800,6528) transpose-cast
// wq/wk/wv; [6528,6536) rect table. All 256-thr.
// ---------------------------------------------------------------------------
__global__ __launch_bounds__(256) void k_prep(
    const float* __restrict__ x, const float* __restrict__ wqkv,
    const float* __restrict__ wq, const float* __restrict__ wk,
    const float* __restrict__ wv,
    bf16* __restrict__ xb, bf16* __restrict__ wqkvb,
    bf16* __restrict__ wqT, bf16* __restrict__ wkT, bf16* __restrict__ wvT,
    int4* __restrict__ rectG, float* __restrict__ invG)
{
  __shared__ float tile[32][33];
  int b = blockIdx.x;
  if (b < 4800) {
    int idx = (b * 256 + threadIdx.x) * 4;
    const int NX = 4096 * 768;
    float4 v;
    bf16* d;
    if (idx < NX) { v = *(const float4*)(x + idx); d = xb + idx; }
    else { v = *(const float4*)(wqkv + (idx - NX)); d = wqkvb + (idx - NX); }
    short4b s = {f2bs(v.x), f2bs(v.y), f2bs(v.z), f2bs(v.w)};
    *(short4b*)d = s;
    return;
  }
  if (b < 6528) {
    int r = b - 4800;
    int z = r / 576; r -= z * 576;
    int by = r / 24, bx = r - by * 24;
    const float* src = (z == 0) ? wq : (z == 1) ? wk : wv;
    bf16* dst = (z == 0) ? wqT : (z == 1) ? wkT : wvT;
    int r0 = by * 32, c0 = bx * 32;
    int lx = threadIdx.x & 31, ly = threadIdx.x >> 5;
#pragma unroll
    for (int yy = 0; yy < 4; ++yy)
      tile[ly + yy * 8][lx] = src[(size_t)(r0 + ly + yy * 8) * 768 + c0 + lx];
    __syncthreads();
#pragma unroll
    for (int yy = 0; yy < 4; ++yy)
      dst[(size_t)(c0 + ly + yy * 8) * 768 + r0 + lx] =
          __float2bfloat16(tile[lx][ly + yy * 8]);
    return;
  }
  int m = (b - 6528) * 256 + threadIdx.x;
  if (m >= NAREA_PAD) return;
  int4 rc = make_int4(0, 0, 0, 0);
  float iv = 0.f;
  if (m < NAREA) {
    int rem = m, ah = 1, aw = 1, found = 0;
    for (int a = 1; a <= 3 && !found; ++a)
      for (int w = 1; w <= 3 && !found; ++w) {
        int np = (17 - a) * (17 - w);
        if (rem < np) { ah = a; aw = w; found = 1; }
        else rem -= np;
      }
    int cw = 17 - aw;
    int y = rem / cw, xx = rem - y * cw;
    rc.x = (y * 17 + xx) * 64;
    rc.y = (y * 17 + (xx + aw)) * 64;
    rc.z = ((y + ah) * 17 + xx) * 64;
    rc.w = ((y + ah) * 17 + (xx + aw)) * 64;
    iv = 1.0f / (float)(ah * aw);
  }
  rectG[m] = rc;
  invG[m] = iv;
}

// ---------------------------------------------------------------------------
// Transpose-cast 768x768 fp32 -> bf16 (for wo, after attn frees Ik region)
// ---------------------------------------------------------------------------
__global__ __launch_bounds__(256) void k_tcast1(
    const float* __restrict__ src, bf16* __restrict__ dst)
{
  __shared__ float tile[32][33];
  int r0 = blockIdx.y * 32, c0 = blockIdx.x * 32;
  int lx = threadIdx.x & 31, ly = threadIdx.x >> 5;
#pragma unroll
  for (int yy = 0; yy < 4; ++yy)
    tile[ly + yy * 8][lx] = src[(size_t)(r0 + ly + yy * 8) * 768 + c0 + lx];
  __syncthreads();
#pragma unroll
  for (int yy = 0; yy < 4; ++yy)
    dst[(size_t)(c0 + ly + yy * 8) * 768 + r0 + lx] =
        __float2bfloat16(tile[lx][ly + yy * 8]);
}

// ===========================================================================
// MFMA GEMM core (BM=128,BN=128,BK=32, 256 thr, 1 barrier/K-tile)
// ===========================================================================

// Wc^T[t][n][m] (bf16) = (wqkv[:,t] @ w_{q,k,v})^T
__global__ __launch_bounds__(256) void k_combine_m(
    const bf16* __restrict__ wqkvb, const bf16* __restrict__ wqT,
    const bf16* __restrict__ wkT, const bf16* __restrict__ wvT,
    bf16* __restrict__ WcTb)
{
  __shared__ __align__(16) short As[2][128 * 32];
  __shared__ __align__(16) short Bs[2][128 * 32];
  const int t3 = blockIdx.z;
  const bf16* BT = (t3 == 0) ? wqT : (t3 == 1) ? wkT : wvT;
  const int m0 = blockIdx.y * 128, n0 = blockIdx.x * 128;
  const int tid = threadIdx.x, lane = tid & 63, w = tid >> 6;
  const int tt = lane & 15, q4 = lane >> 4;
  const int moff = (w & 1) * 64, noff = (w >> 1) * 64;
  const int r_a = tid >> 2, kc = (tid & 3) * 8;

  f32x4 acc[4][4];
#pragma unroll
  for (int i = 0; i < 4; ++i)
#pragma unroll
    for (int j = 0; j < 4; ++j) acc[i][j] = (f32x4){0.f, 0.f, 0.f, 0.f};

  uint4 ra0 = *(const uint4*)(wqkvb + (size_t)(m0 + r_a) * 2304 + t3 * 768 + kc);
  uint4 ra1 = *(const uint4*)(wqkvb + (size_t)(m0 + r_a + 64) * 2304 + t3 * 768 + kc);
  uint4 rb0 = *(const uint4*)(BT + (size_t)(n0 + r_a) * 768 + kc);
  uint4 rb1 = *(const uint4*)(BT + (size_t)(n0 + r_a + 64) * 768 + kc);

  for (int it = 0; it < 24; ++it) {
    short* as = As[it & 1];
    short* bs = Bs[it & 1];
    *(uint4*)&as[r_a * 32 + kc] = ra0;
    *(uint4*)&as[(r_a + 64) * 32 + kc] = ra1;
    *(uint4*)&bs[r_a * 32 + kc] = rb0;
    *(uint4*)&bs[(r_a + 64) * 32 + kc] = rb1;
    if (it < 23) {
      int k0 = (it + 1) * 32;
      ra0 = *(const uint4*)(wqkvb + (size_t)(m0 + r_a) * 2304 + t3 * 768 + k0 + kc);
      ra1 = *(const uint4*)(wqkvb + (size_t)(m0 + r_a + 64) * 2304 + t3 * 768 + k0 + kc);
      rb0 = *(const uint4*)(BT + (size_t)(n0 + r_a) * 768 + k0 + kc);
      rb1 = *(const uint4*)(BT + (size_t)(n0 + r_a + 64) * 768 + k0 + kc);
    }
    __syncthreads();
    short8b afr[4], bfr[4];
#pragma unroll
    for (int mt = 0; mt < 4; ++mt)
      afr[mt] = *(const short8b*)&as[(moff + mt * 16 + tt) * 32 + q4 * 8];
#pragma unroll
    for (int nt = 0; nt < 4; ++nt)
      bfr[nt] = *(const short8b*)&bs[(noff + nt * 16 + tt) * 32 + q4 * 8];
#pragma unroll
    for (int mt = 0; mt < 4; ++mt)
#pragma unroll
      for (int nt = 0; nt < 4; ++nt)
        acc[mt][nt] = __builtin_amdgcn_mfma_f32_16x16x32_bf16(afr[mt], bfr[nt], acc[mt][nt], 0, 0, 0);
  }

  bf16* C = WcTb + (size_t)t3 * 768 * 768;
#pragma unroll
  for (int nt = 0; nt < 4; ++nt) {
    int n = n0 + noff + nt * 16 + tt;
#pragma unroll
    for (int mt = 0; mt < 4; ++mt) {
      int mb = m0 + moff + mt * 16 + q4 * 4;
      short4b v = {f2bs(acc[mt][nt][0]), f2bs(acc[mt][nt][1]),
                   f2bs(acc[mt][nt][2]), f2bs(acc[mt][nt][3])};
      *(short4b*)&C[(size_t)n * 768 + mb] = v;
    }
  }
}

// qh/kh/vh = xb @ Wc[t] + bias, scattered to [(b*12+h)][n][d] bf16
__global__ __launch_bounds__(256) void k_proj_m(
    const bf16* __restrict__ xb, const bf16* __restrict__ WcTb,
    const float* __restrict__ bq, const float* __restrict__ bk,
    const float* __restrict__ bv,
    bf16* __restrict__ qh, bf16* __restrict__ kh, bf16* __restrict__ vh)
{
  __shared__ __align__(16) short As[2][128 * 32];
  __shared__ __align__(16) short Bs[2][128 * 32];
  const int t3 = blockIdx.z;
  const bf16* BT = WcTb + (size_t)t3 * 768 * 768;
  const float* bias = (t3 == 0) ? bq : (t3 == 1) ? bk : bv;
  bf16* dst = (t3 == 0) ? qh : (t3 == 1) ? kh : vh;
  const int m0 = blockIdx.y * 128, n0 = blockIdx.x * 128;
  const int tid = threadIdx.x, lane = tid & 63, w = tid >> 6;
  const int tt = lane & 15, q4 = lane >> 4;
  const int moff = (w & 1) * 64, noff = (w >> 1) * 64;
  const int r_a = tid >> 2, kc = (tid & 3) * 8;

  f32x4 acc[4][4];
#pragma unroll
  for (int i = 0; i < 4; ++i)
#pragma unroll
    for (int j = 0; j < 4; ++j) acc[i][j] = (f32x4){0.f, 0.f, 0.f, 0.f};

  uint4 ra0 = *(const uint4*)(xb + (size_t)(m0 + r_a) * 768 + kc);
  uint4 ra1 = *(const uint4*)(xb + (size_t)(m0 + r_a + 64) * 768 + kc);
  uint4 rb0 = *(const uint4*)(BT + (size_t)(n0 + r_a) * 768 + kc);
  uint4 rb1 = *(const uint4*)(BT + (size_t)(n0 + r_a + 64) * 768 + kc);

  for (int it = 0; it < 24; ++it) {
    short* as = As[it & 1];
    short* bs = Bs[it & 1];
    *(uint4*)&as[r_a * 32 + kc] = ra0;
    *(uint4*)&as[(r_a + 64) * 32 + kc] = ra1;
    *(uint4*)&bs[r_a * 32 + kc] = rb0;
    *(uint4*)&bs[(r_a + 64) * 32 + kc] = rb1;
    if (it < 23) {
      int k0 = (it + 1) * 32;
      ra0 = *(const uint4*)(xb + (size_t)(m0 + r_a) * 768 + k0 + kc);
      ra1 = *(const uint4*)(xb + (size_t)(m0 + r_a + 64) * 768 + k0 + kc);
      rb0 = *(const uint4*)(BT + (size_t)(n0 + r_a) * 768 + k0 + kc);
      rb1 = *(const uint4*)(BT + (size_t)(n0 + r_a + 64) * 768 + k0 + kc);
    }
    __syncthreads();
    short8b afr[4], bfr[4];
#pragma unroll
    for (int mt = 0; mt < 4; ++mt)
      afr[mt] = *(const short8b*)&as[(moff + mt * 16 + tt) * 32 + q4 * 8];
#pragma unroll
    for (int nt = 0; nt < 4; ++nt)
      bfr[nt] = *(const short8b*)&bs[(noff + nt * 16 + tt) * 32 + q4 * 8];
#pragma unroll
    for (int mt = 0; mt < 4; ++mt)
#pragma unroll
      for (int nt = 0; nt < 4; ++nt)
        acc[mt][nt] = __builtin_amdgcn_mfma_f32_16x16x32_bf16(afr[mt], bfr[nt], acc[mt][nt], 0, 0, 0);
  }

#pragma unroll
  for (int nt = 0; nt < 4; ++nt) {
    int c = n0 + noff + nt * 16 + tt;
    float bvv = bias[c];
    int h = c >> 6, d = c & 63;
#pragma unroll
    for (int mt = 0; mt < 4; ++mt) {
#pragma unroll
      for (int r = 0; r < 4; ++r) {
        int m = m0 + moff + mt * 16 + q4 * 4 + r;
        dst[(((size_t)((m >> 8) * 12 + h)) << 14) + ((m & 255) << 6) + d] =
            __float2bfloat16(acc[mt][nt][r] + bvv);
      }
    }
  }
}

// out = gather(attno) @ wo + bo (fp32 out)
__global__ __launch_bounds__(256) void k_out_m(
    const bf16* __restrict__ attno, const bf16* __restrict__ woT,
    const float* __restrict__ bo, float* __restrict__ out)
{
  __shared__ __align__(16) short As[2][128 * 32];
  __shared__ __align__(16) short Bs[2][128 * 32];
  const int m0 = blockIdx.y * 128, n0 = blockIdx.x * 128;
  const int tid = threadIdx.x, lane = tid & 63, w = tid >> 6;
  const int tt = lane & 15, q4 = lane >> 4;
  const int moff = (w & 1) * 64, noff = (w >> 1) * 64;
  const int r_a = tid >> 2, kc = (tid & 3) * 8;

  f32x4 acc[4][4];
#pragma unroll
  for (int i = 0; i < 4; ++i)
#pragma unroll
    for (int j = 0; j < 4; ++j) acc[i][j] = (f32x4){0.f, 0.f, 0.f, 0.f};

  int m_a0 = m0 + r_a, m_a1 = m0 + r_a + 64;
  uint4 ra0 = *(const uint4*)(attno + (((size_t)((m_a0 >> 8) * 12 + (kc >> 6))) << 14) + ((m_a0 & 255) << 6) + (kc & 63));
  uint4 ra1 = *(const uint4*)(attno + (((size_t)((m_a1 >> 8) * 12 + (kc >> 6))) << 14) + ((m_a1 & 255) << 6) + (kc & 63));
  uint4 rb0 = *(const uint4*)(woT + (size_t)(n0 + r_a) * 768 + kc);
  uint4 rb1 = *(const uint4*)(woT + (size_t)(n0 + r_a + 64) * 768 + kc);

  for (int it = 0; it < 24; ++it) {
    short* as = As[it & 1];
    short* bs = Bs[it & 1];
    *(uint4*)&as[r_a * 32 + kc] = ra0;
    *(uint4*)&as[(r_a + 64) * 32 + kc] = ra1;
    *(uint4*)&bs[r_a * 32 + kc] = rb0;
    *(uint4*)&bs[(r_a + 64) * 32 + kc] = rb1;
    if (it < 23) {
      int k = (it + 1) * 32 + kc;
      ra0 = *(const uint4*)(attno + (((size_t)((m_a0 >> 8) * 12 + (k >> 6))) << 14) + ((m_a0 & 255) << 6) + (k & 63));
      ra1 = *(const uint4*)(attno + (((size_t)((m_a1 >> 8) * 12 + (k >> 6))) << 14) + ((m_a1 & 255) << 6) + (k & 63));
      rb0 = *(const uint4*)(woT + (size_t)(n0 + r_a) * 768 + k);
      rb1 = *(const uint4*)(woT + (size_t)(n0 + r_a + 64) * 768 + k);
    }
    __syncthreads();
    short8b afr[4], bfr[4];
#pragma unroll
    for (int mt = 0; mt < 4; ++mt)
      afr[mt] = *(const short8b*)&as[(moff + mt * 16 + tt) * 32 + q4 * 8];
#pragma unroll
    for (int nt = 0; nt < 4; ++nt)
      bfr[nt] = *(const short8b*)&bs[(noff + nt * 16 + tt) * 32 + q4 * 8];
#pragma unroll
    for (int mt = 0; mt < 4; ++mt)
#pragma unroll
      for (int nt = 0; nt < 4; ++nt)
        acc[mt][nt] = __builtin_amdgcn_mfma_f32_16x16x32_bf16(afr[mt], bfr[nt], acc[mt][nt], 0, 0, 0);
  }

#pragma unroll
  for (int nt = 0; nt < 4; ++nt) {
    int c = n0 + noff + nt * 16 + tt;
    float bvv = bo[c];
#pragma unroll
    for (int mt = 0; mt < 4; ++mt)
#pragma unroll
      for (int r = 0; r < 4; ++r) {
        int m = m0 + moff + mt * 16 + q4 * 4 + r;
        out[(size_t)m * 768 + c] = acc[mt][nt][r] + bvv;
      }
  }
}

// ---------------------------------------------------------------------------
// Parallel integral image: block = (bh, mat), 1024 thr, LDS two-pass scan.
// Replaces the latency-serial 128-thr version (256 dependent global RTs).
// ---------------------------------------------------------------------------
__global__ __launch_bounds__(1024) void k_integral_p(
    const bf16* __restrict__ kh, const bf16* __restrict__ vh,
    float* __restrict__ Ik, float* __restrict__ Iv)
{
  __shared__ float sat[17 * 17 * 64];  // 73,984 B
  int bh = blockIdx.x >> 1;
  bool isv = blockIdx.x & 1;
  const bf16* src = (isv ? vh : kh) + ((size_t)bh << 14);
  float* dst = (isv ? Iv : Ik) + (size_t)bh * 18496;
  int tid = threadIdx.x;
  int d = tid & 63;
  int row = tid >> 6;  // 0..15
  // row-scan (x): thread (y=row, d)
  {
    float run = 0.f;
    sat[((row + 1) * 17) * 64 + d] = 0.f;  // col 0
#pragma unroll
    for (int xx = 0; xx < 16; ++xx) {
      run += b2f(src[(row * 16 + xx) * 64 + d]);
      sat[((row + 1) * 17 + (xx + 1)) * 64 + d] = run;
    }
    if (row == 0) {
#pragma unroll
      for (int xx = 0; xx < 17; ++xx) sat[xx * 64 + d] = 0.f;  // row 0
    }
  }
  __syncthreads();
  // col-scan (y): thread (x=row+1, d)
  {
    int x = row + 1;
    float run = 0.f;
#pragma unroll
    for (int y = 1; y <= 16; ++y) {
      run += sat[(y * 17 + x) * 64 + d];
      sat[(y * 17 + x) * 64 + d] = run;
    }
  }
  __syncthreads();
  for (int i = tid; i < 18496; i += 1024) dst[i] = sat[i];
}

// ---------------------------------------------------------------------------
// MFMA flash attention (round-7 structure: 192 blocks, 1024 thr, full areas)
// + software-pipelined staging: tile-(it+1) global loads issue BEFORE the
// barrier; only the LDS writes happen after. 1 barrier/tile.
// ---------------------------------------------------------------------------
__global__ __launch_bounds__(1024) void k_attn_m(
    const bf16* __restrict__ qh, const float* __restrict__ Ik,
    const float* __restrict__ Iv, const int4* __restrict__ rectG,
    const float* __restrict__ invG, bf16* __restrict__ attno)
{
  __shared__ __align__(16) short aK2[2][64 * 72];
  __shared__ __align__(16) short aVt2[2][64 * 72];
  __shared__ __align__(16) short Pb[16][16 * 72];

  const int tid = threadIdx.x;
  const int lane = tid & 63;
  const int w = tid >> 6;
  const int t = lane & 15;
  const int q4 = lane >> 4;
  const int bh = blockIdx.x;

  const float* Ikb = Ik + (size_t)bh * 18496;
  const float* Ivb = Iv + (size_t)bh * 18496;
  const bf16* qbase = qh + ((size_t)bh << 14);

  short8b qf0 = *(const short8b*)(qbase + (w * 16 + t) * 64 + q4 * 8);
  short8b qf1 = *(const short8b*)(qbase + (w * 16 + t) * 64 + 32 + q4 * 8);

  f32x4 O[4];
#pragma unroll
  for (int i = 0; i < 4; ++i) O[i] = (f32x4){0.f, 0.f, 0.f, 0.f};
  float l = 0.f;

  // stage tile 0 directly
  {
    short* aK = aK2[0];
    short* aVt = aVt2[0];
    short vp[4];
#pragma unroll
    for (int i = 0; i < 4; ++i) {
      int j = w * 4 + i;
      int4 rc = rectG[j];
      float iv = invG[j];
      float kc = Ikb[rc.w + lane] - Ikb[rc.y + lane] - Ikb[rc.z + lane] + Ikb[rc.x + lane];
      float vc = Ivb[rc.w + lane] - Ivb[rc.y + lane] - Ivb[rc.z + lane] + Ivb[rc.x + lane];
      aK[j * 72 + lane] = f2bs(kc * iv);
      vp[i] = f2bs(vc);
    }
    *(short4b*)&aVt[lane * 72 + w * 4] = (short4b){vp[0], vp[1], vp[2], vp[3]};
  }

  float kcr[4], vcr[4], ivr[4];
  for (int it = 0; it < 32; ++it) {
    // prefetch tile it+1 global loads BEFORE the barrier
    if (it + 1 < 32) {
      int t0n = (it + 1) * 64;
#pragma unroll
      for (int i = 0; i < 4; ++i) {
        int j = t0n + w * 4 + i;
        int4 rc = rectG[j];
        ivr[i] = invG[j];
        kcr[i] = Ikb[rc.w + lane] - Ikb[rc.y + lane] - Ikb[rc.z + lane] + Ikb[rc.x + lane];
        vcr[i] = Ivb[rc.w + lane] - Ivb[rc.y + lane] - Ivb[rc.z + lane] + Ivb[rc.x + lane];
      }
    }
    __syncthreads();
    const short* aK = aK2[it & 1];
    const short* aVt = aVt2[it & 1];
    if (it + 1 < 32) {
      short* aKn = aK2[(it + 1) & 1];
      short* aVtn = aVt2[(it + 1) & 1];
      short vp[4];
#pragma unroll
      for (int i = 0; i < 4; ++i) {
        aKn[(w * 4 + i) * 72 + lane] = f2bs(kcr[i] * ivr[i]);
        vp[i] = f2bs(vcr[i]);
      }
      *(short4b*)&aVtn[lane * 72 + w * 4] = (short4b){vp[0], vp[1], vp[2], vp[3]};
    }

    const int t0 = it * 64;
    const bool edge = (t0 + 64 > NAREA);
#pragma unroll
    for (int at = 0; at < 4; ++at) {
      short8b af0 = *(const short8b*)&aK[(at * 16 + t) * 72 + q4 * 8];
      short8b af1 = *(const short8b*)&aK[(at * 16 + t) * 72 + 32 + q4 * 8];
      f32x4 s = (f32x4){0.f, 0.f, 0.f, 0.f};
      s = __builtin_amdgcn_mfma_f32_16x16x32_bf16(af0, qf0, s, 0, 0, 0);
      s = __builtin_amdgcn_mfma_f32_16x16x32_bf16(af1, qf1, s, 0, 0, 0);
      float p[4];
#pragma unroll
      for (int r = 0; r < 4; ++r) {
        p[r] = __expf(s[r]);
        if (edge && (t0 + at * 16 + q4 * 4 + r >= NAREA)) p[r] = 0.f;
      }
      l += (p[0] + p[1]) + (p[2] + p[3]);
      short4b pk = (short4b){f2bs(p[0]), f2bs(p[1]), f2bs(p[2]), f2bs(p[3])};
      *(short4b*)&Pb[w][t * 72 + at * 16 + q4 * 4] = pk;
    }
    short8b pf0 = *(const short8b*)&Pb[w][t * 72 + q4 * 8];
    short8b pf1 = *(const short8b*)&Pb[w][t * 72 + 32 + q4 * 8];
#pragma unroll
    for (int nt = 0; nt < 4; ++nt) {
      short8b vf0 = *(const short8b*)&aVt[(nt * 16 + t) * 72 + q4 * 8];
      short8b vf1 = *(const short8b*)&aVt[(nt * 16 + t) * 72 + 32 + q4 * 8];
      O[nt] = __builtin_amdgcn_mfma_f32_16x16x32_bf16(pf0, vf0, O[nt], 0, 0, 0);
      O[nt] = __builtin_amdgcn_mfma_f32_16x16x32_bf16(pf1, vf1, O[nt], 0, 0, 0);
    }
  }

  l += __shfl_xor(l, 16, 64);
  l += __shfl_xor(l, 32, 64);

  bf16* ob = attno + ((size_t)bh << 14);
#pragma unroll
  for (int r = 0; r < 4; ++r) {
    int qrow = q4 * 4 + r;
    float invl = 1.0f / __shfl(l, qrow, 64);
#pragma unroll
    for (int nt = 0; nt < 4; ++nt)
      ob[(w * 16 + qrow) * 64 + nt * 16 + t] = __float2bfloat16(O[nt][r] * invl);
  }
}

extern "C" void kernel_launch(void* const* d_in, const int* in_sizes, int n_in,
                              void* d_out, int out_size, void* d_ws, size_t ws_size,
                              hipStream_t stream) {
  const float* x    = (const float*)d_in[0];
  const float* wqkv = (const float*)d_in[1];
  const float* wq   = (const float*)d_in[2];
  const float* bq   = (const float*)d_in[3];
  const float* wk   = (const float*)d_in[4];
  const float* bk   = (const float*)d_in[5];
  const float* wv   = (const float*)d_in[6];
  const float* bv   = (const float*)d_in[7];
  const float* wo   = (const float*)d_in[8];
  const float* bo   = (const float*)d_in[9];
  float* out = (float*)d_out;

  char* ws = (char*)d_ws;
  char* ob = (char*)d_out;
  const size_t WC_B = 7077888;   // zone A size
  const size_t QH_B = 6291456;   // bf16 [192][256][64]

  // d_out as scratch until k_out_m: xb + WcTb (both dead before k_out_m)
  bf16* xb    = (bf16*)ob;                  // [0, 6291456)
  bf16* WcTb  = (bf16*)(ob + QH_B);         // [6291456, 9830400)
  // ws zone A: attno [0,6291456), rectG/invG after (round-4 lesson: no overlap)
  bf16* attno = (bf16*)ws;
  int4*  rectG = (int4*)(ws + QH_B);             // [6291456, 6324224)
  float* invG  = (float*)(ws + QH_B + 32768);    // [6324224, 6332416) < WC_B
  // qh/kh/vh
  bf16* qh = (bf16*)(ws + WC_B);
  bf16* kh = (bf16*)(ws + WC_B + QH_B);
  bf16* vh = (bf16*)(ws + WC_B + 2 * QH_B);
  // pre-k_proj aliases into (not-yet-written) qh/kh region
  bf16* wqkvb = (bf16*)(ws + WC_B);
  bf16* wqT   = (bf16*)(ws + WC_B + 3538944);
  bf16* wkT   = (bf16*)(ws + WC_B + 4718592);
  bf16* wvT   = (bf16*)(ws + WC_B + 5898240);
  // SAT; woT aliases dead Ik after attn
  float* Ik = (float*)(ws + WC_B + 3 * QH_B);
  float* Iv = Ik + 3551232;                      // total 54,362,112 (known fit)
  bf16* woT = (bf16*)(ws + WC_B + 3 * QH_B);

  k_prep<<<dim3(6536), 256, 0, stream>>>(x, wqkv, wq, wk, wv, xb, wqkvb,
                                         wqT, wkT, wvT, rectG, invG);
  k_combine_m<<<dim3(6, 6, 3), 256, 0, stream>>>(wqkvb, wqT, wkT, wvT, WcTb);
  k_proj_m<<<dim3(6, 32, 3), 256, 0, stream>>>(xb, WcTb, bq, bk, bv, qh, kh, vh);
  k_integral_p<<<dim3(384), 1024, 0, stream>>>(kh, vh, Ik, Iv);
  k_attn_m<<<dim3(192), 1024, 0, stream>>>(qh, Ik, Iv, rectG, invG, attno);
  k_tcast1<<<dim3(24, 24), 256, 0, stream>>>(wo, woT);
  k_out_m<<<dim3(6, 32), 256, 0, stream>>>(attno, woT, bo, out);
}

// Round 10
// 240.476 us; speedup vs baseline: 1.2188x; 1.0091x over previous
//
#include <hip/hip_runtime.h>
#include <hip/hip_bf16.h>

typedef __hip_bfloat16 bf16;
typedef __attribute__((ext_vector_type(8))) short short8b;
typedef __attribute__((ext_vector_type(4))) short short4b;
typedef __attribute__((ext_vector_type(4))) float f32x4;

#define NAREA 2025
#define NAREA_PAD 2048

static __device__ __forceinline__ float b2f(bf16 x) { return __bfloat162float(x); }
static __device__ __forceinline__ short f2bs(float f) {
  bf16 h = __float2bfloat16(f);
  return *(short*)&h;
}

// async global->LDS, 16B/lane; lds base must be wave-uniform (lane*16 added by HW)
static __device__ __forceinline__ void gll16(const void* g, void* l) {
  __builtin_amdgcn_global_load_lds(
      (const __attribute__((address_space(1))) unsigned int*)(unsigned long long)g,
      (__attribute__((address_space(3))) unsigned int*)(unsigned int)(unsigned long long)l,
      16, 0, 0);
}

// ---------------------------------------------------------------------------
// Fused prep: [0,4800) cast x+wqkv; [4800,6528) transpose-cast wq/wk/wv;
// [6528,6536) rect table.
// ---------------------------------------------------------------------------
__global__ __launch_bounds__(256) void k_prep(
    const float* __restrict__ x, const float* __restrict__ wqkv,
    const float* __restrict__ wq, const float* __restrict__ wk,
    const float* __restrict__ wv,
    bf16* __restrict__ xb, bf16* __restrict__ wqkvb,
    bf16* __restrict__ wqT, bf16* __restrict__ wkT, bf16* __restrict__ wvT,
    int4* __restrict__ rectG, float* __restrict__ invG)
{
  __shared__ float tile[32][33];
  int b = blockIdx.x;
  if (b < 4800) {
    int idx = (b * 256 + threadIdx.x) * 4;
    const int NX = 4096 * 768;
    float4 v;
    bf16* d;
    if (idx < NX) { v = *(const float4*)(x + idx); d = xb + idx; }
    else { v = *(const float4*)(wqkv + (idx - NX)); d = wqkvb + (idx - NX); }
    short4b s = {f2bs(v.x), f2bs(v.y), f2bs(v.z), f2bs(v.w)};
    *(short4b*)d = s;
    return;
  }
  if (b < 6528) {
    int r = b - 4800;
    int z = r / 576; r -= z * 576;
    int by = r / 24, bx = r - by * 24;
    const float* src = (z == 0) ? wq : (z == 1) ? wk : wv;
    bf16* dst = (z == 0) ? wqT : (z == 1) ? wkT : wvT;
    int r0 = by * 32, c0 = bx * 32;
    int lx = threadIdx.x & 31, ly = threadIdx.x >> 5;
#pragma unroll
    for (int yy = 0; yy < 4; ++yy)
      tile[ly + yy * 8][lx] = src[(size_t)(r0 + ly + yy * 8) * 768 + c0 + lx];
    __syncthreads();
#pragma unroll
    for (int yy = 0; yy < 4; ++yy)
      dst[(size_t)(c0 + ly + yy * 8) * 768 + r0 + lx] =
          __float2bfloat16(tile[lx][ly + yy * 8]);
    return;
  }
  int m = (b - 6528) * 256 + threadIdx.x;
  if (m >= NAREA_PAD) return;
  int4 rc = make_int4(0, 0, 0, 0);
  float iv = 0.f;
  if (m < NAREA) {
    int rem = m, ah = 1, aw = 1, found = 0;
    for (int a = 1; a <= 3 && !found; ++a)
      for (int w = 1; w <= 3 && !found; ++w) {
        int np = (17 - a) * (17 - w);
        if (rem < np) { ah = a; aw = w; found = 1; }
        else rem -= np;
      }
    int cw = 17 - aw;
    int y = rem / cw, xx = rem - y * cw;
    rc.x = (y * 17 + xx) * 64;
    rc.y = (y * 17 + (xx + aw)) * 64;
    rc.z = ((y + ah) * 17 + xx) * 64;
    rc.w = ((y + ah) * 17 + (xx + aw)) * 64;
    iv = 1.0f / (float)(ah * aw);
  }
  rectG[m] = rc;
  invG[m] = iv;
}

// ---------------------------------------------------------------------------
// Transpose-cast 768x768 fp32 -> bf16 (wo; runs after attn frees Ik region)
// ---------------------------------------------------------------------------
__global__ __launch_bounds__(256) void k_tcast1(
    const float* __restrict__ src, bf16* __restrict__ dst)
{
  __shared__ float tile[32][33];
  int r0 = blockIdx.y * 32, c0 = blockIdx.x * 32;
  int lx = threadIdx.x & 31, ly = threadIdx.x >> 5;
#pragma unroll
  for (int yy = 0; yy < 4; ++yy)
    tile[ly + yy * 8][lx] = src[(size_t)(r0 + ly + yy * 8) * 768 + c0 + lx];
  __syncthreads();
#pragma unroll
  for (int yy = 0; yy < 4; ++yy)
    dst[(size_t)(c0 + ly + yy * 8) * 768 + r0 + lx] =
        __float2bfloat16(tile[lx][ly + yy * 8]);
}

// ===========================================================================
// MFMA GEMM core (BM=BN=128, BK=32, 256 thr): staging via global_load_lds
// width=16 issued AFTER the barrier into the other buffer (m97 pattern);
// the next barrier's vmcnt drain completes it. 1 barrier/K-tile.
// Dest mapping: thread tid -> as + tid*16B == wave base (w*1024B) + lane*16.
// ===========================================================================

// Wc^T[t][n][m] (bf16) = (wqkv[:,t] @ w_{q,k,v})^T
__global__ __launch_bounds__(256) void k_combine_m(
    const bf16* __restrict__ wqkvb, const bf16* __restrict__ wqT,
    const bf16* __restrict__ wkT, const bf16* __restrict__ wvT,
    bf16* __restrict__ WcTb)
{
  __shared__ __align__(16) short As[2][128 * 32];
  __shared__ __align__(16) short Bs[2][128 * 32];
  const int t3 = blockIdx.z;
  const bf16* BT = (t3 == 0) ? wqT : (t3 == 1) ? wkT : wvT;
  const int m0 = blockIdx.y * 128, n0 = blockIdx.x * 128;
  const int tid = threadIdx.x, lane = tid & 63, w = tid >> 6;
  const int tt = lane & 15, q4 = lane >> 4;
  const int moff = (w & 1) * 64, noff = (w >> 1) * 64;
  const int r_a = tid >> 2, kc = (tid & 3) * 8;

  f32x4 acc[4][4];
#pragma unroll
  for (int i = 0; i < 4; ++i)
#pragma unroll
    for (int j = 0; j < 4; ++j) acc[i][j] = (f32x4){0.f, 0.f, 0.f, 0.f};

#define STAGE_C(k0, buf)                                                        \
  {                                                                             \
    gll16(wqkvb + (size_t)(m0 + r_a) * 2304 + t3 * 768 + (k0) + kc,             \
          &As[buf][w * 512]);                                                   \
    gll16(wqkvb + (size_t)(m0 + r_a + 64) * 2304 + t3 * 768 + (k0) + kc,        \
          &As[buf][2048 + w * 512]);                                            \
    gll16(BT + (size_t)(n0 + r_a) * 768 + (k0) + kc, &Bs[buf][w * 512]);        \
    gll16(BT + (size_t)(n0 + r_a + 64) * 768 + (k0) + kc,                       \
          &Bs[buf][2048 + w * 512]);                                            \
  }

  STAGE_C(0, 0);
  for (int it = 0; it < 24; ++it) {
    __syncthreads();
    if (it < 23) STAGE_C((it + 1) * 32, (it + 1) & 1);
    const short* as = As[it & 1];
    const short* bs = Bs[it & 1];
    short8b afr[4], bfr[4];
#pragma unroll
    for (int mt = 0; mt < 4; ++mt)
      afr[mt] = *(const short8b*)&as[(moff + mt * 16 + tt) * 32 + q4 * 8];
#pragma unroll
    for (int nt = 0; nt < 4; ++nt)
      bfr[nt] = *(const short8b*)&bs[(noff + nt * 16 + tt) * 32 + q4 * 8];
#pragma unroll
    for (int mt = 0; mt < 4; ++mt)
#pragma unroll
      for (int nt = 0; nt < 4; ++nt)
        acc[mt][nt] = __builtin_amdgcn_mfma_f32_16x16x32_bf16(afr[mt], bfr[nt], acc[mt][nt], 0, 0, 0);
  }
#undef STAGE_C

  bf16* C = WcTb + (size_t)t3 * 768 * 768;
#pragma unroll
  for (int nt = 0; nt < 4; ++nt) {
    int n = n0 + noff + nt * 16 + tt;
#pragma unroll
    for (int mt = 0; mt < 4; ++mt) {
      int mb = m0 + moff + mt * 16 + q4 * 4;
      short4b v = {f2bs(acc[mt][nt][0]), f2bs(acc[mt][nt][1]),
                   f2bs(acc[mt][nt][2]), f2bs(acc[mt][nt][3])};
      *(short4b*)&C[(size_t)n * 768 + mb] = v;
    }
  }
}

// qh/kh/vh = xb @ Wc[t] + bias, scattered to [(b*12+h)][n][d] bf16
__global__ __launch_bounds__(256) void k_proj_m(
    const bf16* __restrict__ xb, const bf16* __restrict__ WcTb,
    const float* __restrict__ bq, const float* __restrict__ bk,
    const float* __restrict__ bv,
    bf16* __restrict__ qh, bf16* __restrict__ kh, bf16* __restrict__ vh)
{
  __shared__ __align__(16) short As[2][128 * 32];
  __shared__ __align__(16) short Bs[2][128 * 32];
  const int t3 = blockIdx.z;
  const bf16* BT = WcTb + (size_t)t3 * 768 * 768;
  const float* bias = (t3 == 0) ? bq : (t3 == 1) ? bk : bv;
  bf16* dst = (t3 == 0) ? qh : (t3 == 1) ? kh : vh;
  const int m0 = blockIdx.y * 128, n0 = blockIdx.x * 128;
  const int tid = threadIdx.x, lane = tid & 63, w = tid >> 6;
  const int tt = lane & 15, q4 = lane >> 4;
  const int moff = (w & 1) * 64, noff = (w >> 1) * 64;
  const int r_a = tid >> 2, kc = (tid & 3) * 8;

  f32x4 acc[4][4];
#pragma unroll
  for (int i = 0; i < 4; ++i)
#pragma unroll
    for (int j = 0; j < 4; ++j) acc[i][j] = (f32x4){0.f, 0.f, 0.f, 0.f};

#define STAGE_P(k0, buf)                                                        \
  {                                                                             \
    gll16(xb + (size_t)(m0 + r_a) * 768 + (k0) + kc, &As[buf][w * 512]);        \
    gll16(xb + (size_t)(m0 + r_a + 64) * 768 + (k0) + kc,                       \
          &As[buf][2048 + w * 512]);                                            \
    gll16(BT + (size_t)(n0 + r_a) * 768 + (k0) + kc, &Bs[buf][w * 512]);        \
    gll16(BT + (size_t)(n0 + r_a + 64) * 768 + (k0) + kc,                       \
          &Bs[buf][2048 + w * 512]);                                            \
  }

  STAGE_P(0, 0);
  for (int it = 0; it < 24; ++it) {
    __syncthreads();
    if (it < 23) STAGE_P((it + 1) * 32, (it + 1) & 1);
    const short* as = As[it & 1];
    const short* bs = Bs[it & 1];
    short8b afr[4], bfr[4];
#pragma unroll
    for (int mt = 0; mt < 4; ++mt)
      afr[mt] = *(const short8b*)&as[(moff + mt * 16 + tt) * 32 + q4 * 8];
#pragma unroll
    for (int nt = 0; nt < 4; ++nt)
      bfr[nt] = *(const short8b*)&bs[(noff + nt * 16 + tt) * 32 + q4 * 8];
#pragma unroll
    for (int mt = 0; mt < 4; ++mt)
#pragma unroll
      for (int nt = 0; nt < 4; ++nt)
        acc[mt][nt] = __builtin_amdgcn_mfma_f32_16x16x32_bf16(afr[mt], bfr[nt], acc[mt][nt], 0, 0, 0);
  }
#undef STAGE_P

#pragma unroll
  for (int nt = 0; nt < 4; ++nt) {
    int c = n0 + noff + nt * 16 + tt;
    float bvv = bias[c];
    int h = c >> 6, d = c & 63;
#pragma unroll
    for (int mt = 0; mt < 4; ++mt) {
#pragma unroll
      for (int r = 0; r < 4; ++r) {
        int m = m0 + moff + mt * 16 + q4 * 4 + r;
        dst[(((size_t)((m >> 8) * 12 + h)) << 14) + ((m & 255) << 6) + d] =
            __float2bfloat16(acc[mt][nt][r] + bvv);
      }
    }
  }
}

// out = gather(attno) @ wo + bo (fp32 out)
__global__ __launch_bounds__(256) void k_out_m(
    const bf16* __restrict__ attno, const bf16* __restrict__ woT,
    const float* __restrict__ bo, float* __restrict__ out)
{
  __shared__ __align__(16) short As[2][128 * 32];
  __shared__ __align__(16) short Bs[2][128 * 32];
  const int m0 = blockIdx.y * 128, n0 = blockIdx.x * 128;
  const int tid = threadIdx.x, lane = tid & 63, w = tid >> 6;
  const int tt = lane & 15, q4 = lane >> 4;
  const int moff = (w & 1) * 64, noff = (w >> 1) * 64;
  const int r_a = tid >> 2, kc = (tid & 3) * 8;
  const int m_a0 = m0 + r_a, m_a1 = m0 + r_a + 64;

  f32x4 acc[4][4];
#pragma unroll
  for (int i = 0; i < 4; ++i)
#pragma unroll
    for (int j = 0; j < 4; ++j) acc[i][j] = (f32x4){0.f, 0.f, 0.f, 0.f};

#define STAGE_O(k0, buf)                                                        \
  {                                                                             \
    int k = (k0) + kc;                                                          \
    gll16(attno + (((size_t)((m_a0 >> 8) * 12 + (k >> 6))) << 14) +             \
              ((m_a0 & 255) << 6) + (k & 63),                                   \
          &As[buf][w * 512]);                                                   \
    gll16(attno + (((size_t)((m_a1 >> 8) * 12 + (k >> 6))) << 14) +             \
              ((m_a1 & 255) << 6) + (k & 63),                                   \
          &As[buf][2048 + w * 512]);                                            \
    gll16(woT + (size_t)(n0 + r_a) * 768 + k, &Bs[buf][w * 512]);               \
    gll16(woT + (size_t)(n0 + r_a + 64) * 768 + k, &Bs[buf][2048 + w * 512]);   \
  }

  STAGE_O(0, 0);
  for (int it = 0; it < 24; ++it) {
    __syncthreads();
    if (it < 23) STAGE_O((it + 1) * 32, (it + 1) & 1);
    const short* as = As[it & 1];
    const short* bs = Bs[it & 1];
    short8b afr[4], bfr[4];
#pragma unroll
    for (int mt = 0; mt < 4; ++mt)
      afr[mt] = *(const short8b*)&as[(moff + mt * 16 + tt) * 32 + q4 * 8];
#pragma unroll
    for (int nt = 0; nt < 4; ++nt)
      bfr[nt] = *(const short8b*)&bs[(noff + nt * 16 + tt) * 32 + q4 * 8];
#pragma unroll
    for (int mt = 0; mt < 4; ++mt)
#pragma unroll
      for (int nt = 0; nt < 4; ++nt)
        acc[mt][nt] = __builtin_amdgcn_mfma_f32_16x16x32_bf16(afr[mt], bfr[nt], acc[mt][nt], 0, 0, 0);
  }
#undef STAGE_O

#pragma unroll
  for (int nt = 0; nt < 4; ++nt) {
    int c = n0 + noff + nt * 16 + tt;
    float bvv = bo[c];
#pragma unroll
    for (int mt = 0; mt < 4; ++mt)
#pragma unroll
      for (int r = 0; r < 4; ++r) {
        int m = m0 + moff + mt * 16 + q4 * 4 + r;
        out[(size_t)m * 768 + c] = acc[mt][nt][r] + bvv;
      }
  }
}

// ---------------------------------------------------------------------------
// Parallel integral image: block = (bh, mat), 1024 thr, LDS two-pass scan.
// ---------------------------------------------------------------------------
__global__ __launch_bounds__(1024) void k_integral_p(
    const bf16* __restrict__ kh, const bf16* __restrict__ vh,
    float* __restrict__ Ik, float* __restrict__ Iv)
{
  __shared__ float sat[17 * 17 * 64];
  int bh = blockIdx.x >> 1;
  bool isv = blockIdx.x & 1;
  const bf16* src = (isv ? vh : kh) + ((size_t)bh << 14);
  float* dst = (isv ? Iv : Ik) + (size_t)bh * 18496;
  int tid = threadIdx.x;
  int d = tid & 63;
  int row = tid >> 6;
  {
    float run = 0.f;
    sat[((row + 1) * 17) * 64 + d] = 0.f;
#pragma unroll
    for (int xx = 0; xx < 16; ++xx) {
      run += b2f(src[(row * 16 + xx) * 64 + d]);
      sat[((row + 1) * 17 + (xx + 1)) * 64 + d] = run;
    }
    if (row == 0) {
#pragma unroll
      for (int xx = 0; xx < 17; ++xx) sat[xx * 64 + d] = 0.f;
    }
  }
  __syncthreads();
  {
    int x = row + 1;
    float run = 0.f;
#pragma unroll
    for (int y = 1; y <= 16; ++y) {
      run += sat[(y * 17 + x) * 64 + d];
      sat[(y * 17 + x) * 64 + d] = run;
    }
  }
  __syncthreads();
  for (int i = tid; i < 18496; i += 1024) dst[i] = sat[i];
}

// ---------------------------------------------------------------------------
// MFMA flash attention with FREE P-transpose: QK's at-th MFMA reads permuted
// aK rows so that C regs land exactly in PV A-fragment layout. Pb eliminated.
//   QK at-MFMA A row (lane t) = (at>>1)*32 + (t&12)*2 + (at&1)*4 + (t&3)
//   => lane (t,q4) reg r = P[area=(at>>1)*32+q4*8+(at&1)*4+r][query=t]
//   => apv[chunk=at>>1] shorts j=(at&1)*4+r  (A[m=t][k=q4*8+j], k==area) ✓
// aK stride 80 keeps permuted b128 reads bank-balanced ((2row+q4) mod 8 unif).
// ---------------------------------------------------------------------------
__global__ __launch_bounds__(1024) void k_attn_m(
    const bf16* __restrict__ qh, const float* __restrict__ Ik,
    const float* __restrict__ Iv, const int4* __restrict__ rectG,
    const float* __restrict__ invG, bf16* __restrict__ attno)
{
  __shared__ __align__(16) short aK2[2][64 * 80];
  __shared__ __align__(16) short aVt2[2][64 * 72];

  const int tid = threadIdx.x;
  const int lane = tid & 63;
  const int w = tid >> 6;
  const int t = lane & 15;
  const int q4 = lane >> 4;
  const int bh = blockIdx.x;
  const int rbase = (t & 12) * 2 + (t & 3);

  const float* Ikb = Ik + (size_t)bh * 18496;
  const float* Ivb = Iv + (size_t)bh * 18496;
  const bf16* qbase = qh + ((size_t)bh << 14);

  short8b qf0 = *(const short8b*)(qbase + (w * 16 + t) * 64 + q4 * 8);
  short8b qf1 = *(const short8b*)(qbase + (w * 16 + t) * 64 + 32 + q4 * 8);

  f32x4 O[4];
#pragma unroll
  for (int i = 0; i < 4; ++i) O[i] = (f32x4){0.f, 0.f, 0.f, 0.f};
  float l = 0.f;

  // stage tile 0
  {
    short* aK = aK2[0];
    short* aVt = aVt2[0];
    short vp[4];
#pragma unroll
    for (int i = 0; i < 4; ++i) {
      int j = w * 4 + i;
      int4 rc = rectG[j];
      float iv = invG[j];
      float kc = Ikb[rc.w + lane] - Ikb[rc.y + lane] - Ikb[rc.z + lane] + Ikb[rc.x + lane];
      float vc = Ivb[rc.w + lane] - Ivb[rc.y + lane] - Ivb[rc.z + lane] + Ivb[rc.x + lane];
      aK[j * 80 + lane] = f2bs(kc * iv);
      vp[i] = f2bs(vc);
    }
    *(short4b*)&aVt[lane * 72 + w * 4] = (short4b){vp[0], vp[1], vp[2], vp[3]};
  }

  float kcr[4], vcr[4], ivr[4];
  for (int it = 0; it < 32; ++it) {
    if (it + 1 < 32) {
      int t0n = (it + 1) * 64;
#pragma unroll
      for (int i = 0; i < 4; ++i) {
        int j = t0n + w * 4 + i;
        int4 rc = rectG[j];
        ivr[i] = invG[j];
        kcr[i] = Ikb[rc.w + lane] - Ikb[rc.y + lane] - Ikb[rc.z + lane] + Ikb[rc.x + lane];
        vcr[i] = Ivb[rc.w + lane] - Ivb[rc.y + lane] - Ivb[rc.z + lane] + Ivb[rc.x + lane];
      }
    }
    __syncthreads();
    const short* aK = aK2[it & 1];
    const short* aVt = aVt2[it & 1];
    if (it + 1 < 32) {
      short* aKn = aK2[(it + 1) & 1];
      short* aVtn = aVt2[(it + 1) & 1];
      short vp[4];
#pragma unroll
      for (int i = 0; i < 4; ++i) {
        aKn[(w * 4 + i) * 80 + lane] = f2bs(kcr[i] * ivr[i]);
        vp[i] = f2bs(vcr[i]);
      }
      *(short4b*)&aVtn[lane * 72 + w * 4] = (short4b){vp[0], vp[1], vp[2], vp[3]};
    }

    const int t0 = it * 64;
    const bool edge = (t0 + 64 > NAREA);
    union { short8b v; unsigned u[4]; } apv[2];
#pragma unroll
    for (int at = 0; at < 4; ++at) {
      int row = rbase + (at & 1) * 4 + (at >> 1) * 32;
      short8b af0 = *(const short8b*)&aK[row * 80 + q4 * 8];
      short8b af1 = *(const short8b*)&aK[row * 80 + 32 + q4 * 8];
      f32x4 s = (f32x4){0.f, 0.f, 0.f, 0.f};
      s = __builtin_amdgcn_mfma_f32_16x16x32_bf16(af0, qf0, s, 0, 0, 0);
      s = __builtin_amdgcn_mfma_f32_16x16x32_bf16(af1, qf1, s, 0, 0, 0);
      int abase = t0 + (at >> 1) * 32 + q4 * 8 + (at & 1) * 4;
      float p[4];
#pragma unroll
      for (int r = 0; r < 4; ++r) {
        p[r] = __expf(s[r]);
        if (edge && (abase + r >= NAREA)) p[r] = 0.f;
      }
      l += (p[0] + p[1]) + (p[2] + p[3]);
      unsigned lo = ((unsigned)(unsigned short)f2bs(p[1]) << 16) |
                    (unsigned short)f2bs(p[0]);
      unsigned hi = ((unsigned)(unsigned short)f2bs(p[3]) << 16) |
                    (unsigned short)f2bs(p[2]);
      apv[at >> 1].u[(at & 1) * 2 + 0] = lo;
      apv[at >> 1].u[(at & 1) * 2 + 1] = hi;
    }
#pragma unroll
    for (int nt = 0; nt < 4; ++nt) {
      short8b vf0 = *(const short8b*)&aVt[(nt * 16 + t) * 72 + q4 * 8];
      short8b vf1 = *(const short8b*)&aVt[(nt * 16 + t) * 72 + 32 + q4 * 8];
      O[nt] = __builtin_amdgcn_mfma_f32_16x16x32_bf16(apv[0].v, vf0, O[nt], 0, 0, 0);
      O[nt] = __builtin_amdgcn_mfma_f32_16x16x32_bf16(apv[1].v, vf1, O[nt], 0, 0, 0);
    }
  }

  l += __shfl_xor(l, 16, 64);
  l += __shfl_xor(l, 32, 64);

  bf16* ob = attno + ((size_t)bh << 14);
#pragma unroll
  for (int r = 0; r < 4; ++r) {
    int qrow = q4 * 4 + r;
    float invl = 1.0f / __shfl(l, qrow, 64);
#pragma unroll
    for (int nt = 0; nt < 4; ++nt)
      ob[(w * 16 + qrow) * 64 + nt * 16 + t] = __float2bfloat16(O[nt][r] * invl);
  }
}

extern "C" void kernel_launch(void* const* d_in, const int* in_sizes, int n_in,
                              void* d_out, int out_size, void* d_ws, size_t ws_size,
                              hipStream_t stream) {
  const float* x    = (const float*)d_in[0];
  const float* wqkv = (const float*)d_in[1];
  const float* wq   = (const float*)d_in[2];
  const float* bq   = (const float*)d_in[3];
  const float* wk   = (const float*)d_in[4];
  const float* bk   = (const float*)d_in[5];
  const float* wv   = (const float*)d_in[6];
  const float* bv   = (const float*)d_in[7];
  const float* wo   = (const float*)d_in[8];
  const float* bo   = (const float*)d_in[9];
  float* out = (float*)d_out;

  char* ws = (char*)d_ws;
  char* ob = (char*)d_out;
  const size_t WC_B = 7077888;   // zone A size
  const size_t QH_B = 6291456;   // bf16 [192][256][64]

  // d_out as scratch until k_out_m: xb + WcTb (both dead before k_out_m)
  bf16* xb    = (bf16*)ob;                  // [0, 6291456)
  bf16* WcTb  = (bf16*)(ob + QH_B);         // [6291456, 9830400)
  // ws zone A: attno [0,6291456), rectG/invG after (no overlap — round-4 lesson)
  bf16* attno = (bf16*)ws;
  int4*  rectG = (int4*)(ws + QH_B);             // [6291456, 6324224)
  float* invG  = (float*)(ws + QH_B + 32768);    // [6324224, 6332416) < WC_B
  // qh/kh/vh
  bf16* qh = (bf16*)(ws + WC_B);
  bf16* kh = (bf16*)(ws + WC_B + QH_B);
  bf16* vh = (bf16*)(ws + WC_B + 2 * QH_B);
  // pre-k_proj aliases into (not-yet-written) qh/kh region
  bf16* wqkvb = (bf16*)(ws + WC_B);
  bf16* wqT   = (bf16*)(ws + WC_B + 3538944);
  bf16* wkT   = (bf16*)(ws + WC_B + 4718592);
  bf16* wvT   = (bf16*)(ws + WC_B + 5898240);
  // SAT; woT aliases dead Ik after attn
  float* Ik = (float*)(ws + WC_B + 3 * QH_B);
  float* Iv = Ik + 3551232;                      // total 54,362,112 (known fit)
  bf16* woT = (bf16*)(ws + WC_B + 3 * QH_B);

  k_prep<<<dim3(6536), 256, 0, stream>>>(x, wqkv, wq, wk, wv, xb, wqkvb,
                                         wqT, wkT, wvT, rectG, invG);
  k_combine_m<<<dim3(6, 6, 3), 256, 0, stream>>>(wqkvb, wqT, wkT, wvT, WcTb);
  k_proj_m<<<dim3(6, 32, 3), 256, 0, stream>>>(xb, WcTb, bq, bk, bv, qh, kh, vh);
  k_integral_p<<<dim3(384), 1024, 0, stream>>>(kh, vh, Ik, Iv);
  k_attn_m<<<dim3(192), 1024, 0, stream>>>(qh, Ik, Iv, rectG, invG, attno);
  k_tcast1<<<dim3(24, 24), 256, 0, stream>>>(wo, woT);
  k_out_m<<<dim3(6, 32), 256, 0, stream>>>(attno, woT, bo, out);
}